// Round 1
// baseline (8610.754 us; speedup 1.0000x reference)
//
#include <hip/hip_runtime.h>
#include <hip/hip_bf16.h>
#include <stdint.h>

#define B_  2048
#define D_  512
#define M_  32768
#define H_  4
#define HD_ 128
#define K_  64

// ---------------------------------------------------------------------------
// GEMM: C[n][o] = sum_j X[n][j] * W[o][j] + bias[o]   (all fp32, NT layout)
// X: N x 512 row-major, W: 512 x 512 row-major, C: N x 512
// Tiles 128x128, BK=16, 256 threads, 8x8 per thread.
// ---------------------------------------------------------------------------
__global__ __launch_bounds__(256) void gemm_nt_bias(
    const float* __restrict__ X, const float* __restrict__ W,
    const float* __restrict__ bias, float* __restrict__ C, int N) {
  __shared__ float As[16][132];
  __shared__ float Bs[16][132];
  const int t  = threadIdx.x;
  const int tx = t & 15, ty = t >> 4;
  const int rowbase = blockIdx.x * 128;
  const int colbase = blockIdx.y * 128;
  float acc[8][8];
  #pragma unroll
  for (int i = 0; i < 8; ++i)
    #pragma unroll
    for (int j = 0; j < 8; ++j) acc[i][j] = 0.f;

  for (int k0 = 0; k0 < 512; k0 += 16) {
    #pragma unroll
    for (int i = 0; i < 2; ++i) {
      int idx = t + i * 256;
      int r = idx >> 2, kq = idx & 3;
      float4 v = *(const float4*)&X[(size_t)(rowbase + r) * 512 + k0 + kq * 4];
      As[kq*4+0][r] = v.x; As[kq*4+1][r] = v.y;
      As[kq*4+2][r] = v.z; As[kq*4+3][r] = v.w;
      float4 w = *(const float4*)&W[(size_t)(colbase + r) * 512 + k0 + kq * 4];
      Bs[kq*4+0][r] = w.x; Bs[kq*4+1][r] = w.y;
      Bs[kq*4+2][r] = w.z; Bs[kq*4+3][r] = w.w;
    }
    __syncthreads();
    #pragma unroll
    for (int k = 0; k < 16; ++k) {
      float a[8], b[8];
      *(float4*)&a[0] = *(const float4*)&As[k][ty*8];
      *(float4*)&a[4] = *(const float4*)&As[k][ty*8+4];
      *(float4*)&b[0] = *(const float4*)&Bs[k][tx*8];
      *(float4*)&b[4] = *(const float4*)&Bs[k][tx*8+4];
      #pragma unroll
      for (int i = 0; i < 8; ++i)
        #pragma unroll
        for (int j = 0; j < 8; ++j)
          acc[i][j] = fmaf(a[i], b[j], acc[i][j]);
    }
    __syncthreads();
  }
  #pragma unroll
  for (int i = 0; i < 8; ++i) {
    size_t r = (size_t)(rowbase + ty*8 + i);
    #pragma unroll
    for (int j4 = 0; j4 < 2; ++j4) {
      int c = colbase + tx*8 + j4*4;
      float4 bv = *(const float4*)&bias[c];
      float4 o;
      o.x = acc[i][j4*4+0] + bv.x;
      o.y = acc[i][j4*4+1] + bv.y;
      o.z = acc[i][j4*4+2] + bv.z;
      o.w = acc[i][j4*4+3] + bv.w;
      *(float4*)&C[r * 512 + c] = o;
    }
  }
}

// ---------------------------------------------------------------------------
// Fused scores + running top-64.
// Grid (B/32, H), 256 threads (4 waves). Wave w owns rows rowbase+8w..+7.
// Chunk = 64 candidate keys staged in LDS (XOR-swizzled 16B blocks).
// Lane <-> candidate column; Q read via scalar (SGPR) loads.
// Top-64 list per row lives in registers, lane <-> slot.
// Tie-breaking matches jax.lax.top_k (keep lowest index).
// ---------------------------------------------------------------------------
__global__ __launch_bounds__(256) void scores_topk(
    const float* __restrict__ Qp, const float* __restrict__ Kp,
    float* __restrict__ tks, int* __restrict__ tki) {
  __shared__ __align__(16) float Ks[64 * 128];
  const int t    = threadIdx.x;
  const int wid  = t >> 6, lane = t & 63;
  const int h    = blockIdx.y;
  const int rowbase = blockIdx.x * 32;
  // force SGPR (uniform) base for Q so the compiler emits s_load
  const int rb = __builtin_amdgcn_readfirstlane(rowbase + wid * 8);
  const float* qb = Qp + (size_t)rb * 512 + (size_t)h * 128;
  const size_t kcol = (size_t)h * 128;

  float4 pre[8];
  auto load_regs = [&](int mb) {
    #pragma unroll
    for (int i = 0; i < 8; ++i) {
      int idx = t + i * 256;
      int c = idx >> 5, bd = idx & 31;
      pre[i] = *(const float4*)&Kp[(size_t)(mb + c) * 512 + kcol + bd * 4];
    }
  };
  auto store_lds = [&]() {
    #pragma unroll
    for (int i = 0; i < 8; ++i) {
      int idx = t + i * 256;
      int c = idx >> 5, bd = idx & 31;
      *(float4*)&Ks[(c << 7) + ((bd ^ (c & 7)) << 2)] = pre[i];
    }
  };

  float ls[8], thr[8];
  int   li[8];
  const int lb = lane & 7;
  const float SCALE = 0.08838834764831843f; // 1/sqrt(128)

  load_regs(0);
  store_lds();
  __syncthreads();

  for (int mb = 0; mb < M_; mb += 64) {
    const bool more = (mb + 64) < M_;
    if (more) load_regs(mb + 64);   // overlap global latency with compute

    float acc[8];
    #pragma unroll
    for (int r = 0; r < 8; ++r) acc[r] = 0.f;

    #pragma unroll 2
    for (int db = 0; db < 32; db += 4) {
      float kk[16];
      #pragma unroll
      for (int u = 0; u < 4; ++u)
        *(float4*)&kk[u * 4] =
            *(const float4*)&Ks[(lane << 7) + (((db + u) ^ lb) << 2)];
      #pragma unroll
      for (int j = 0; j < 16; ++j) {
        #pragma unroll
        for (int r = 0; r < 8; ++r)
          acc[r] = fmaf(qb[r * 512 + db * 4 + j], kk[j], acc[r]);
      }
    }

    if (mb == 0) {
      // first chunk exactly fills the 64-entry list
      #pragma unroll
      for (int r = 0; r < 8; ++r) {
        float s = acc[r] * SCALE;
        ls[r] = s; li[r] = lane;
        float m = s;
        #pragma unroll
        for (int off = 32; off; off >>= 1) m = fminf(m, __shfl_xor(m, off));
        thr[r] = m;
      }
    } else {
      #pragma unroll
      for (int r = 0; r < 8; ++r) {
        float s = acc[r] * SCALE;
        unsigned long long mask = __ballot(s > thr[r]);
        if (mask) {
          do {
            int src = __ffsll((long long)mask) - 1; mask &= mask - 1;
            float cs = __shfl(s, src);
            int   cm = mb + src;
            // argmin over list; tie -> evict larger index (keep lower index)
            float bs = ls[r]; int bi = li[r]; int bp = lane;
            #pragma unroll
            for (int off = 32; off; off >>= 1) {
              float os = __shfl_xor(bs, off);
              int   oi = __shfl_xor(bi, off);
              int   op = __shfl_xor(bp, off);
              if (os < bs || (os == bs && oi > bi)) { bs = os; bi = oi; bp = op; }
            }
            if (cs > bs && lane == bp) { ls[r] = cs; li[r] = cm; }
          } while (mask);
          float m2 = ls[r];
          #pragma unroll
          for (int off = 32; off; off >>= 1) m2 = fminf(m2, __shfl_xor(m2, off));
          thr[r] = m2;
        }
      }
    }

    if (more) {
      __syncthreads();
      store_lds();
      __syncthreads();
    }
  }

  #pragma unroll
  for (int r = 0; r < 8; ++r) {
    size_t o = (((size_t)(rowbase + wid * 8 + r)) * H_ + h) * 64 + lane;
    tks[o] = ls[r];
    tki[o] = li[r];
  }
}

// ---------------------------------------------------------------------------
// Softmax over top-64 + V gather + weighted sum.  Grid (B*H), 128 threads.
// ---------------------------------------------------------------------------
__global__ __launch_bounds__(128) void attend(
    const float* __restrict__ tks, const int* __restrict__ tki,
    const float* __restrict__ Vp, float* __restrict__ att) {
  __shared__ float wsm[64];
  __shared__ int   widx[64];
  const int bh = blockIdx.x;
  const int b = bh >> 2, h = bh & 3;
  const int t = threadIdx.x;
  if (t < 64) {
    float s = tks[(size_t)bh * 64 + t];
    float m = s;
    #pragma unroll
    for (int off = 32; off; off >>= 1) m = fmaxf(m, __shfl_xor(m, off));
    float e = expf(s - m);
    float z = e;
    #pragma unroll
    for (int off = 32; off; off >>= 1) z += __shfl_xor(z, off);
    wsm[t]  = e / z;
    widx[t] = tki[(size_t)bh * 64 + t];
  }
  __syncthreads();
  float a = 0.f;
  #pragma unroll 4
  for (int k = 0; k < 64; ++k)
    a = fmaf(wsm[k], Vp[(size_t)widx[k] * 512 + h * 128 + t], a);
  att[(size_t)b * 512 + h * 128 + t] = a;
}

// ---------------------------------------------------------------------------
extern "C" void kernel_launch(void* const* d_in, const int* in_sizes, int n_in,
                              void* d_out, int out_size, void* d_ws, size_t ws_size,
                              hipStream_t stream) {
  const float* query  = (const float*)d_in[0];
  const float* memory = (const float*)d_in[1];
  const float* Wq = (const float*)d_in[2];
  const float* bq = (const float*)d_in[3];
  const float* Wk = (const float*)d_in[4];
  const float* bk = (const float*)d_in[5];
  const float* Wv = (const float*)d_in[6];
  const float* bv = (const float*)d_in[7];
  const float* Wo = (const float*)d_in[8];
  const float* bo = (const float*)d_in[9];
  float* out = (float*)d_out;

  // workspace layout (fp32 elements)
  float* Qp  = (float*)d_ws;                    //  2048*512   (4 MB)
  float* Kp  = Qp  + (size_t)B_ * D_;           // 32768*512   (64 MB)
  float* Vp  = Kp  + (size_t)M_ * D_;           // 32768*512   (64 MB)
  float* att = Vp  + (size_t)M_ * D_;           //  2048*512   (4 MB)
  float* tks = att + (size_t)B_ * D_;           //  8192*64    (2 MB)
  int*   tki = (int*)(tks + (size_t)B_ * H_ * K_); // 2 MB

  gemm_nt_bias<<<dim3(B_ / 128, 4), 256, 0, stream>>>(query,  Wq, bq, Qp, B_);
  gemm_nt_bias<<<dim3(M_ / 128, 4), 256, 0, stream>>>(memory, Wk, bk, Kp, M_);
  gemm_nt_bias<<<dim3(M_ / 128, 4), 256, 0, stream>>>(memory, Wv, bv, Vp, M_);
  scores_topk<<<dim3(B_ / 32, H_), 256, 0, stream>>>(Qp, Kp, tks, tki);
  attend<<<dim3(B_ * H_), 128, 0, stream>>>(tks, tki, Vp, att);
  gemm_nt_bias<<<dim3(B_ / 128, 4), 256, 0, stream>>>(att, Wo, bo, out, B_);
}

// Round 2
// 5221.545 us; speedup vs baseline: 1.6491x; 1.6491x over previous
//
#include <hip/hip_runtime.h>
#include <hip/hip_bf16.h>
#include <stdint.h>

#define B_  2048
#define D_  512
#define M_  32768
#define H_  4
#define HD_ 128
#define K_  64
#define MS_ 4               // M-split factor for scores_topk occupancy
#define SLICE_ (M_ / MS_)   // 8192 candidates per WG

// ---------------------------------------------------------------------------
// GEMM: C[n][o] = sum_j X[n][j] * W[o][j] + bias[o]   (all fp32, NT layout)
// ---------------------------------------------------------------------------
__global__ __launch_bounds__(256) void gemm_nt_bias(
    const float* __restrict__ X, const float* __restrict__ W,
    const float* __restrict__ bias, float* __restrict__ C, int N) {
  __shared__ float As[16][132];
  __shared__ float Bs[16][132];
  const int t  = threadIdx.x;
  const int tx = t & 15, ty = t >> 4;
  const int rowbase = blockIdx.x * 128;
  const int colbase = blockIdx.y * 128;
  float acc[8][8];
  #pragma unroll
  for (int i = 0; i < 8; ++i)
    #pragma unroll
    for (int j = 0; j < 8; ++j) acc[i][j] = 0.f;

  for (int k0 = 0; k0 < 512; k0 += 16) {
    #pragma unroll
    for (int i = 0; i < 2; ++i) {
      int idx = t + i * 256;
      int r = idx >> 2, kq = idx & 3;
      float4 v = *(const float4*)&X[(size_t)(rowbase + r) * 512 + k0 + kq * 4];
      As[kq*4+0][r] = v.x; As[kq*4+1][r] = v.y;
      As[kq*4+2][r] = v.z; As[kq*4+3][r] = v.w;
      float4 w = *(const float4*)&W[(size_t)(colbase + r) * 512 + k0 + kq * 4];
      Bs[kq*4+0][r] = w.x; Bs[kq*4+1][r] = w.y;
      Bs[kq*4+2][r] = w.z; Bs[kq*4+3][r] = w.w;
    }
    __syncthreads();
    #pragma unroll
    for (int k = 0; k < 16; ++k) {
      float a[8], b[8];
      *(float4*)&a[0] = *(const float4*)&As[k][ty*8];
      *(float4*)&a[4] = *(const float4*)&As[k][ty*8+4];
      *(float4*)&b[0] = *(const float4*)&Bs[k][tx*8];
      *(float4*)&b[4] = *(const float4*)&Bs[k][tx*8+4];
      #pragma unroll
      for (int i = 0; i < 8; ++i)
        #pragma unroll
        for (int j = 0; j < 8; ++j)
          acc[i][j] = fmaf(a[i], b[j], acc[i][j]);
    }
    __syncthreads();
  }
  #pragma unroll
  for (int i = 0; i < 8; ++i) {
    size_t r = (size_t)(rowbase + ty*8 + i);
    #pragma unroll
    for (int j4 = 0; j4 < 2; ++j4) {
      int c = colbase + tx*8 + j4*4;
      float4 bv = *(const float4*)&bias[c];
      float4 o;
      o.x = acc[i][j4*4+0] + bv.x;
      o.y = acc[i][j4*4+1] + bv.y;
      o.z = acc[i][j4*4+2] + bv.z;
      o.w = acc[i][j4*4+3] + bv.w;
      *(float4*)&C[r * 512 + c] = o;
    }
  }
}

// ---------------------------------------------------------------------------
// Fused scores + running top-64 over an M-slice.
// Grid (B/32, H, MS_), 256 threads (4 waves). Wave w owns 8 q-rows.
// Chunk = 64 candidate keys staged in LDS (XOR-swizzled 16B blocks).
// Per-slice top-64 lists in registers (lane <-> slot), ballot-gated insert.
// Tie-breaking matches jax.lax.top_k (keep lowest index).
// ---------------------------------------------------------------------------
__global__ __launch_bounds__(256) void scores_topk(
    const float* __restrict__ Qp, const float* __restrict__ Kp,
    float* __restrict__ tks, int* __restrict__ tki) {
  __shared__ __align__(16) float Ks[64 * 128];
  const int t    = threadIdx.x;
  const int wid  = t >> 6, lane = t & 63;
  const int h    = blockIdx.y;
  const int rowbase = blockIdx.x * 32;
  const int mbase = blockIdx.z * SLICE_;
  const int mend  = mbase + SLICE_;
  // force SGPR (uniform) base for Q so the compiler emits s_load
  const int rb = __builtin_amdgcn_readfirstlane(rowbase + wid * 8);
  const float* qb = Qp + (size_t)rb * 512 + (size_t)h * 128;
  const size_t kcol = (size_t)h * 128;

  float4 pre[8];
  auto load_regs = [&](int mb) {
    #pragma unroll
    for (int i = 0; i < 8; ++i) {
      int idx = t + i * 256;
      int c = idx >> 5, bd = idx & 31;
      pre[i] = *(const float4*)&Kp[(size_t)(mb + c) * 512 + kcol + bd * 4];
    }
  };
  auto store_lds = [&]() {
    #pragma unroll
    for (int i = 0; i < 8; ++i) {
      int idx = t + i * 256;
      int c = idx >> 5, bd = idx & 31;
      *(float4*)&Ks[(c << 7) + ((bd ^ (c & 7)) << 2)] = pre[i];
    }
  };

  float ls[8], thr[8];
  int   li[8];
  const int lb = lane & 7;
  const float SCALE = 0.08838834764831843f; // 1/sqrt(128)

  load_regs(mbase);
  store_lds();
  __syncthreads();

  for (int mb = mbase; mb < mend; mb += 64) {
    const bool more = (mb + 64) < mend;
    if (more) load_regs(mb + 64);   // overlap global latency with compute

    float acc[8];
    #pragma unroll
    for (int r = 0; r < 8; ++r) acc[r] = 0.f;

    #pragma unroll 2
    for (int db = 0; db < 32; db += 4) {
      float kk[16];
      #pragma unroll
      for (int u = 0; u < 4; ++u)
        *(float4*)&kk[u * 4] =
            *(const float4*)&Ks[(lane << 7) + (((db + u) ^ lb) << 2)];
      #pragma unroll
      for (int j = 0; j < 16; ++j) {
        #pragma unroll
        for (int r = 0; r < 8; ++r)
          acc[r] = fmaf(qb[r * 512 + db * 4 + j], kk[j], acc[r]);
      }
    }

    if (mb == mbase) {
      // first chunk exactly fills the 64-entry list
      #pragma unroll
      for (int r = 0; r < 8; ++r) {
        float s = acc[r] * SCALE;
        ls[r] = s; li[r] = mbase + lane;
        float m = s;
        #pragma unroll
        for (int off = 32; off; off >>= 1) m = fminf(m, __shfl_xor(m, off));
        thr[r] = m;
      }
    } else {
      #pragma unroll
      for (int r = 0; r < 8; ++r) {
        float s = acc[r] * SCALE;
        unsigned long long mask = __ballot(s > thr[r]);
        if (mask) {
          do {
            int src = __ffsll((long long)mask) - 1; mask &= mask - 1;
            float cs = __shfl(s, src);
            int   cm = mb + src;
            // argmin over list; tie -> evict larger index (keep lower index)
            float bs = ls[r]; int bi = li[r]; int bp = lane;
            #pragma unroll
            for (int off = 32; off; off >>= 1) {
              float os = __shfl_xor(bs, off);
              int   oi = __shfl_xor(bi, off);
              int   op = __shfl_xor(bp, off);
              if (os < bs || (os == bs && oi > bi)) { bs = os; bi = oi; bp = op; }
            }
            if (cs > bs && lane == bp) { ls[r] = cs; li[r] = cm; }
          } while (mask);
          float m2 = ls[r];
          #pragma unroll
          for (int off = 32; off; off >>= 1) m2 = fminf(m2, __shfl_xor(m2, off));
          thr[r] = m2;
        }
      }
    }

    if (more) {
      __syncthreads();
      store_lds();
      __syncthreads();
    }
  }

  #pragma unroll
  for (int r = 0; r < 8; ++r) {
    size_t o = ((((size_t)(rowbase + wid * 8 + r)) * H_ + h) * MS_ + blockIdx.z) * 64 + lane;
    tks[o] = ls[r];
    tki[o] = li[r];
  }
}

// ---------------------------------------------------------------------------
// Merge MS_*64 = 256 per-slice candidates -> top-64, per (b,h).
// Bitonic sort by (score desc, idx asc) == jax.lax.top_k semantics.
// ---------------------------------------------------------------------------
__global__ __launch_bounds__(128) void topk_merge(
    const float* __restrict__ tks, const int* __restrict__ tki,
    float* __restrict__ mtks, int* __restrict__ mtki) {
  __shared__ float s_[256];
  __shared__ int   i_[256];
  const int bh = blockIdx.x;
  const int t  = threadIdx.x;
  s_[t]       = tks[(size_t)bh * 256 + t];
  i_[t]       = tki[(size_t)bh * 256 + t];
  s_[t + 128] = tks[(size_t)bh * 256 + t + 128];
  i_[t + 128] = tki[(size_t)bh * 256 + t + 128];
  __syncthreads();
  for (int k = 2; k <= 256; k <<= 1) {
    for (int j = k >> 1; j > 0; j >>= 1) {
      int i = ((t & ~(j - 1)) << 1) | (t & (j - 1));
      int p = i | j;
      bool dir = ((i & k) == 0);
      float sa = s_[i], sb = s_[p];
      int   ia = i_[i], ib = i_[p];
      bool inorder = (sa > sb) || (sa == sb && ia <= ib);
      if (inorder != dir) { s_[i] = sb; s_[p] = sa; i_[i] = ib; i_[p] = ia; }
      __syncthreads();
    }
  }
  if (t < 64) {
    mtks[(size_t)bh * 64 + t] = s_[t];
    mtki[(size_t)bh * 64 + t] = i_[t];
  }
}

// ---------------------------------------------------------------------------
// Softmax over top-64 + V gather + weighted sum.  Grid (B*H), 128 threads.
// ---------------------------------------------------------------------------
__global__ __launch_bounds__(128) void attend(
    const float* __restrict__ mtks, const int* __restrict__ mtki,
    const float* __restrict__ Vp, float* __restrict__ att) {
  __shared__ float wsm[64];
  __shared__ int   widx[64];
  const int bh = blockIdx.x;
  const int b = bh >> 2, h = bh & 3;
  const int t = threadIdx.x;
  if (t < 64) {
    float s = mtks[(size_t)bh * 64 + t];
    float m = s;
    #pragma unroll
    for (int off = 32; off; off >>= 1) m = fmaxf(m, __shfl_xor(m, off));
    float e = expf(s - m);
    float z = e;
    #pragma unroll
    for (int off = 32; off; off >>= 1) z += __shfl_xor(z, off);
    wsm[t]  = e / z;
    widx[t] = mtki[(size_t)bh * 64 + t];
  }
  __syncthreads();
  float a = 0.f;
  #pragma unroll 4
  for (int k = 0; k < 64; ++k)
    a = fmaf(wsm[k], Vp[(size_t)widx[k] * 512 + h * 128 + t], a);
  att[(size_t)b * 512 + h * 128 + t] = a;
}

// ---------------------------------------------------------------------------
extern "C" void kernel_launch(void* const* d_in, const int* in_sizes, int n_in,
                              void* d_out, int out_size, void* d_ws, size_t ws_size,
                              hipStream_t stream) {
  const float* query  = (const float*)d_in[0];
  const float* memory = (const float*)d_in[1];
  const float* Wq = (const float*)d_in[2];
  const float* bq = (const float*)d_in[3];
  const float* Wk = (const float*)d_in[4];
  const float* bk = (const float*)d_in[5];
  const float* Wv = (const float*)d_in[6];
  const float* bv = (const float*)d_in[7];
  const float* Wo = (const float*)d_in[8];
  const float* bo = (const float*)d_in[9];
  float* out = (float*)d_out;

  // workspace layout (fp32 elements)
  float* Qp  = (float*)d_ws;                        //  2048*512      (4 MB)
  float* Kp  = Qp  + (size_t)B_ * D_;               // 32768*512     (64 MB)
  float* Vp  = Kp  + (size_t)M_ * D_;               // 32768*512     (64 MB)
  float* att = Vp  + (size_t)M_ * D_;               //  2048*512      (4 MB)
  float* tks = att + (size_t)B_ * D_;               //  B*H*MS*64     (8 MB)
  int*   tki = (int*)(tks + (size_t)B_ * H_ * MS_ * K_);            // (8 MB)
  // merged lists alias Qp's space (Qp dead after scores_topk): 4 MB needed
  float* mtks = Qp;                                  // B*H*64 (2 MB)
  int*   mtki = (int*)(mtks + (size_t)B_ * H_ * K_); //        (2 MB)

  gemm_nt_bias<<<dim3(B_ / 128, 4), 256, 0, stream>>>(query,  Wq, bq, Qp, B_);
  gemm_nt_bias<<<dim3(M_ / 128, 4), 256, 0, stream>>>(memory, Wk, bk, Kp, M_);
  gemm_nt_bias<<<dim3(M_ / 128, 4), 256, 0, stream>>>(memory, Wv, bv, Vp, M_);
  scores_topk<<<dim3(B_ / 32, H_, MS_), 256, 0, stream>>>(Qp, Kp, tks, tki);
  topk_merge<<<dim3(B_ * H_), 128, 0, stream>>>(tks, tki, mtks, mtki);
  attend<<<dim3(B_ * H_), 128, 0, stream>>>(mtks, mtki, Vp, att);
  gemm_nt_bias<<<dim3(B_ / 128, 4), 256, 0, stream>>>(att, Wo, bo, out, B_);
}